// Round 11
// baseline (255.657 us; speedup 1.0000x reference)
//
#include <hip/hip_runtime.h>
#include <cstdint>
#include <cstddef>

#define B_DIM 2048
#define D_DIM 64
#define N_DIM 16384
#define H_DIM 4
#define DOUT_DIM 256
#define NOUT (H_DIM*DOUT_DIM)   // 1024

typedef __bf16 bf16;
typedef __bf16 bf16x4 __attribute__((ext_vector_type(4)));
typedef __bf16 bf16x8 __attribute__((ext_vector_type(8)));
typedef float f32x4 __attribute__((ext_vector_type(4)));

#define LOG2E 1.44269504088896340736f

// ---------------------------------------------------------------------------
// K0: fused prep.
#define PREP_RBLK 4096
#define PREP_XBLK 512
__global__ void k_prep(const float* __restrict__ x, const float* __restrict__ R,
                       bf16* __restrict__ xh, bf16* __restrict__ xl,
                       bf16* __restrict__ Rh, bf16* __restrict__ Rl,
                       float* __restrict__ r2) {
    int blk = blockIdx.x, t = threadIdx.x;
    if (blk < PREP_RBLK) {
        int lane = t & 63, wave = t >> 6;
        int row = blk * 4 + wave;
        float v = R[row * 64 + lane];
        bf16 h = (bf16)v;
        Rh[row * 64 + lane] = h;
        Rl[row * 64 + lane] = (bf16)(v - (float)h);
        float s = v * v;
        #pragma unroll
        for (int off = 32; off > 0; off >>= 1) s += __shfl_xor(s, off, 64);
        if (lane == 0) r2[row] = s;
    } else {
        int i = (blk - PREP_RBLK) * 256 + t;        // B*D = 131072 total
        float f = 2.0f * x[i];
        bf16 h = (bf16)f;
        xh[i] = h;
        xl[i] = (bf16)(f - (float)h);
    }
}

// K0d: Vt[h*256+d][n] = bf16(W[h][n][d] / (relu(q[h][n])+eps))
__global__ void k_build_V(const float* __restrict__ W, const float* __restrict__ q_raw,
                          bf16* __restrict__ Vt) {
    __shared__ float tile[64][33];
    __shared__ float qprow[64];
    int h = blockIdx.z, d0 = blockIdx.y * 32, n0 = blockIdx.x * 64;
    int t = threadIdx.x;
    int tj = t & 31, ti = t >> 5;   // ti: 0..7
    if (t < 64)
        qprow[t] = 1.0f / (fmaxf(q_raw[h * N_DIM + n0 + t], 0.0f) + 1e-12f);
    #pragma unroll
    for (int ii = 0; ii < 8; ++ii) {
        int i = ti + ii * 8;        // n-local 0..63
        tile[i][tj] = W[((size_t)(h * N_DIM) + (n0 + i)) * DOUT_DIM + d0 + tj];
    }
    __syncthreads();
    int d = t >> 3, nq = t & 7;     // d-local 0..31, n-quad 0..7
    bf16x8 ov;
    #pragma unroll
    for (int j = 0; j < 8; ++j) {
        int n = nq * 8 + j;
        ov[j] = (bf16)(tile[n][d] * qprow[n]);
    }
    *(bf16x8*)(Vt + (size_t)(h * DOUT_DIM + d0 + d) * N_DIM + n0 + nq * 8) = ov;
}

// K2: scores via split-bf16 MFMA (3 products), e = exp(s) -> bf16.
// UNCHANGED (no counters for it yet; only k_gemm geometry changes).
__launch_bounds__(256)
__global__ void k_scores(const bf16* __restrict__ xh, const bf16* __restrict__ xl,
                         const bf16* __restrict__ Rh, const bf16* __restrict__ Rl,
                         const float* __restrict__ r2, const float* __restrict__ q_raw,
                         bf16* __restrict__ e, float* __restrict__ Spart) {
    __shared__ bf16 eT[128][136];   // [b-local][key-local], padded rows
    __shared__ float qp[4][128];
    int n0 = blockIdx.x * 128;      // key tile
    int row0 = blockIdx.y * 128;    // b tile
    int t = threadIdx.x;
    int lane = t & 63, w = t >> 6;
    int wr = w >> 1, wc = w & 1;    // wave owns keys wr*64.., b's wc*64..
    #pragma unroll
    for (int rr = 0; rr < 2; ++rr) {
        int ii = t + rr * 256;      // 0..511 = 4 heads x 128 keys
        qp[ii >> 7][ii & 127] =
            1.0f / (fmaxf(q_raw[(ii >> 7) * N_DIM + n0 + (ii & 127)], 0.0f) + 1e-12f);
    }
    int l15 = lane & 15, l4 = lane >> 4;
    f32x4 acc[4][4] = {};
    #pragma unroll
    for (int kk = 0; kk < 2; ++kk) {
        bf16x8 bxh[4], bxl[4];
        #pragma unroll
        for (int ni = 0; ni < 4; ++ni) {
            int b = row0 + wc * 64 + ni * 16 + l15;
            size_t off = (size_t)b * 64 + kk * 32 + l4 * 8;
            bxh[ni] = *(const bf16x8*)(xh + off);
            bxl[ni] = *(const bf16x8*)(xl + off);
        }
        #pragma unroll
        for (int mi = 0; mi < 4; ++mi) {
            int n = n0 + wr * 64 + mi * 16 + l15;
            size_t off = (size_t)n * 64 + kk * 32 + l4 * 8;
            bf16x8 arh = *(const bf16x8*)(Rh + off);
            bf16x8 arl = *(const bf16x8*)(Rl + off);
            #pragma unroll
            for (int ni = 0; ni < 4; ++ni) {
                acc[mi][ni] = __builtin_amdgcn_mfma_f32_16x16x32_bf16(arh, bxh[ni], acc[mi][ni], 0, 0, 0);
                acc[mi][ni] = __builtin_amdgcn_mfma_f32_16x16x32_bf16(arh, bxl[ni], acc[mi][ni], 0, 0, 0);
                acc[mi][ni] = __builtin_amdgcn_mfma_f32_16x16x32_bf16(arl, bxh[ni], acc[mi][ni], 0, 0, 0);
            }
        }
    }
    #pragma unroll
    for (int mi = 0; mi < 4; ++mi) {
        int keyb = wr * 64 + mi * 16 + l4 * 4;          // 4 consecutive local keys
        f32x4 r2v = *(const f32x4*)(r2 + n0 + keyb);
        #pragma unroll
        for (int ni = 0; ni < 4; ++ni) {
            int bloc = wc * 64 + ni * 16 + l15;
            bf16x4 ev;
            #pragma unroll
            for (int j = 0; j < 4; ++j) {
                float s = acc[mi][ni][j] - r2v[j];
                ev[j] = (bf16)exp2f(s * LOG2E);
            }
            *(bf16x4*)(&eT[bloc][keyb]) = ev;
        }
    }
    __syncthreads();
    {
        int bloc = t >> 1, half = t & 1;
        int b = row0 + bloc;
        bf16x8 chunk[8];
        #pragma unroll
        for (int i = 0; i < 8; ++i)
            chunk[i] = *(const bf16x8*)(&eT[bloc][half * 64 + i * 8]);
        bf16x8* gp = (bf16x8*)(e + (size_t)b * N_DIM + n0 + half * 64);
        #pragma unroll
        for (int i = 0; i < 8; ++i) gp[i] = chunk[i];
        float s0 = 0, s1 = 0, s2 = 0, s3 = 0;
        #pragma unroll
        for (int i = 0; i < 8; ++i) {
            #pragma unroll
            for (int jj = 0; jj < 8; ++jj) {
                int nl = half * 64 + i * 8 + jj;
                float ef = (float)chunk[i][jj];
                s0 += ef * qp[0][nl]; s1 += ef * qp[1][nl];
                s2 += ef * qp[2][nl]; s3 += ef * qp[3][nl];
            }
        }
        s0 += __shfl_xor(s0, 1, 64);
        s1 += __shfl_xor(s1, 1, 64);
        s2 += __shfl_xor(s2, 1, 64);
        s3 += __shfl_xor(s3, 1, 64);
        if (half == 0) {
            f32x4 sv = {s0, s1, s2, s3};
            *(f32x4*)(Spart + ((size_t)blockIdx.x * B_DIM + b) * 4) = sv;
        }
    }
}

// K2b: Sinv[b][h] = 1 / (sum_kt Spart[kt][b][h] + eps)
__global__ void k_sreduce(const float* __restrict__ Spart, float* __restrict__ Sinv) {
    int i = blockIdx.x * 256 + threadIdx.x;     // 8192 = 2048*4
    float s = 0.f;
    #pragma unroll 8
    for (int kt = 0; kt < N_DIM / 128; ++kt) s += Spart[(size_t)kt * (B_DIM * 4) + i];
    Sinv[i] = 1.0f / (s + 1e-12f);
}

// K3: split-K GEMM  parts[z][2048][1024] = e @ Vt^T (K-slice z)
// ROUND 11: 256^2 tile, 8 waves (2M x 4N), SAME verified schedule as round
// 10 (2-deep 2x64KB LDS, steady vmcnt(8), raw s_barrier, T2 swizzle
// [conflicts 25.2M->0 verified], T5 setprio, T1 XCD chunking).
// Round-10 post-mortem: 70us @ MfmaUtil 41.5% -- per-MFMA LDS/stage
// overhead is the lever. 256^2: 64 MFMA/wave/K-step @ 0.375 ds_read/MFMA
// (was 32 @ 0.5), A/B panel re-reads halve (FETCH 85 -> ~55MB).
// 512 thr = 8 waves/CU = 2/SIMD (same TLP as round 10). ksplit=8 -> 256
// blocks = exactly 1/CU, one batch; kiters=32. vmcnt ledger UNCHANGED:
// 8 gload-lds/wave/STAGE (4 issues x 2 arrays), 2 tiles in flight ->
// vmcnt(8) waits tile t. acc[8][4] f32x4 = 128 VGPR; est total ~200-230.
__launch_bounds__(512)
__global__ void k_gemm(const bf16* __restrict__ e, const bf16* __restrict__ Vt,
                       float* __restrict__ parts, int kiters) {
    __shared__ bf16 AB[2][2][16384];     // [buf][A/B][256 rows x 64 k] = 128 KB
    int t = threadIdx.x;
    int lane = t & 63, w = t >> 6;       // w: 0..7
    int wr = w >> 2, wc = w & 3;         // wave rows wr*128.., cols wc*64..
    // --- XCD swizzle (T1): grid (4,8,ksplit); each XCD gets nwg/8 contiguous
    // orig ids; x fastest inside -> A-panel sharers co-resident ---
    int nwg = gridDim.x * gridDim.y * gridDim.z;
    int cpx = nwg >> 3;
    int flat = blockIdx.x + 4 * blockIdx.y + 32 * blockIdx.z;
    int orig = (flat & 7) * cpx + (flat >> 3);
    int bx = orig & 3;                   // col tile (0..3)
    int by = (orig >> 2) & 7;            // row tile (0..7)
    int bz = orig >> 5;                  // K-slice
    int brow = by * 256;
    int bcol = bx * 256;
    int kbase = bz * kiters * 64;
    int l15 = lane & 15, l4 = lane >> 4;
    const char* eC  = (const char*)e;
    const char* VtC = (const char*)Vt;
    // pre-swizzled source column within the 128B row segment (T2, rule #21):
    // dest (linear) col = (lane&7)*16, row&7 = lane>>3 -> src col = dest ^ ((row&7)<<4)
    int scolswz = (((lane & 7) ^ (lane >> 3)) << 4);
    int srow = lane >> 3;

#define STAGE(bi, tile) do {                                                              \
    size_t acol = (size_t)(kbase + (tile) * 64) * 2 + scolswz;                            \
    _Pragma("unroll")                                                                     \
    for (int j_ = 0; j_ < 4; ++j_) {                                                      \
        int chunk_ = j_ * 8 + w;         /* 0..31: 8-row chunks of 256 rows */            \
        int row_ = chunk_ * 8 + srow;                                                     \
        __builtin_amdgcn_global_load_lds(                                                 \
            (const __attribute__((address_space(1))) void*)(eC + (size_t)(brow + row_) * (N_DIM*2) + acol), \
            (__attribute__((address_space(3))) void*)((char*)&AB[bi][0][0] + chunk_ * 1024), 16, 0, 0); \
        __builtin_amdgcn_global_load_lds(                                                 \
            (const __attribute__((address_space(1))) void*)(VtC + (size_t)(bcol + row_) * (N_DIM*2) + acol), \
            (__attribute__((address_space(3))) void*)((char*)&AB[bi][1][0] + chunk_ * 1024), 16, 0, 0); \
    }                                                                                     \
} while (0)

#define COMPUTE(bi) do {                                                                  \
    const bf16* As_ = &AB[bi][0][0];                                                      \
    const bf16* Bs_ = &AB[bi][1][0];                                                      \
    _Pragma("unroll")                                                                     \
    for (int kk = 0; kk < 2; ++kk) {                                                      \
        bf16x8 bfr[4], afr[8];                                                            \
        _Pragma("unroll")                                                                 \
        for (int ni = 0; ni < 4; ++ni) {                                                  \
            int row_ = wc * 64 + ni * 16 + l15;                                           \
            int col_ = (kk * 32 + l4 * 8) ^ ((row_ & 7) << 3);                            \
            bfr[ni] = *(const bf16x8*)(Bs_ + row_ * 64 + col_);                           \
        }                                                                                 \
        _Pragma("unroll")                                                                 \
        for (int mi = 0; mi < 8; ++mi) {                                                  \
            int row_ = wr * 128 + mi * 16 + l15;                                          \
            int col_ = (kk * 32 + l4 * 8) ^ ((row_ & 7) << 3);                            \
            afr[mi] = *(const bf16x8*)(As_ + row_ * 64 + col_);                           \
        }                                                                                 \
        _Pragma("unroll")                                                                 \
        for (int mi = 0; mi < 8; ++mi)                                                    \
            _Pragma("unroll")                                                             \
            for (int ni = 0; ni < 4; ++ni)                                                \
                acc[mi][ni] = __builtin_amdgcn_mfma_f32_16x16x32_bf16(afr[mi], bfr[ni], acc[mi][ni], 0, 0, 0); \
    }                                                                                     \
} while (0)

    f32x4 acc[8][4] = {};
    // prologue: prefetch tiles 0,1 into bufs 0,1 (16 loads in flight/wave)
    STAGE(0, 0);
    STAGE(1, 1);
    // main loop: wait tile t (8 newer stay in flight), compute t, stage t+2
    for (int kt = 0; kt <= kiters - 3; ++kt) {
        int bi = kt & 1;
        asm volatile("s_waitcnt vmcnt(8)" ::: "memory");
        __builtin_amdgcn_sched_barrier(0);
        asm volatile("s_barrier" ::: "memory");
        __builtin_amdgcn_s_setprio(1);
        COMPUTE(bi);
        __builtin_amdgcn_s_setprio(0);
        asm volatile("s_barrier" ::: "memory");
        STAGE(bi, kt + 2);               // buf (kt+2)&1 == kt&1
    }
    // 2-step tail: vmcnt 8 / 0
    {
        asm volatile("s_waitcnt vmcnt(8)" ::: "memory");
        __builtin_amdgcn_sched_barrier(0);
        asm volatile("s_barrier" ::: "memory");
        COMPUTE((kiters - 2) & 1);
        asm volatile("s_barrier" ::: "memory");
    }
    {
        asm volatile("s_waitcnt vmcnt(0)" ::: "memory");
        __builtin_amdgcn_sched_barrier(0);
        asm volatile("s_barrier" ::: "memory");
        COMPUTE((kiters - 1) & 1);
    }
#undef STAGE
#undef COMPUTE
    float* P = parts + (size_t)bz * ((size_t)B_DIM * NOUT);
    #pragma unroll
    for (int mi = 0; mi < 8; ++mi) {
        #pragma unroll
        for (int j = 0; j < 4; ++j) {
            int r = brow + wr * 128 + mi * 16 + l4 * 4 + j;
            #pragma unroll
            for (int ni = 0; ni < 4; ++ni) {
                int c = bcol + wc * 64 + ni * 16 + l15;
                P[(size_t)r * NOUT + c] = acc[mi][ni][j];
            }
        }
    }
}

// K4: out[b][c] = (sum_z parts[z][b][c]) * Sinv[b][c>>8]
__global__ void k_final(const float* __restrict__ parts, const float* __restrict__ Sinv,
                        float* __restrict__ out, int nks) {
    int i4 = blockIdx.x * 256 + threadIdx.x;    // 524288 quads
    size_t base = (size_t)i4 * 4;
    f32x4 s = {0.f, 0.f, 0.f, 0.f};
    for (int k = 0; k < nks; ++k)
        s += *(const f32x4*)(parts + (size_t)k * ((size_t)B_DIM * NOUT) + base);
    int b = i4 >> 8;
    int c = (i4 << 2) & 1023;
    float inv = Sinv[b * 4 + (c >> 8)];
    *(f32x4*)(out + base) = s * inv;
}

extern "C" void kernel_launch(void* const* d_in, const int* in_sizes, int n_in,
                              void* d_out, int out_size, void* d_ws, size_t ws_size,
                              hipStream_t stream) {
    const float* x     = (const float*)d_in[0];   // (2048, 64)
    const float* R     = (const float*)d_in[1];   // (16384, 64)
    const float* q_raw = (const float*)d_in[2];   // (4, 16384)
    const float* W     = (const float*)d_in[3];   // (4, 16384, 256)
    float* out = (float*)d_out;                    // (2048, 4, 256)

    char* ws = (char*)d_ws;
    size_t off = 0;
    auto alloc = [&](size_t bytes) {
        void* p = ws + off;
        off += (bytes + 255) & ~(size_t)255;
        return p;
    };
    bf16*  Vt    = (bf16*) alloc((size_t)NOUT * N_DIM * 2);          // 32 MB
    bf16*  eM    = (bf16*) alloc((size_t)B_DIM * N_DIM * 2);         // 64 MB
    bf16*  xh    = (bf16*) alloc((size_t)B_DIM * D_DIM * 2);
    bf16*  xl    = (bf16*) alloc((size_t)B_DIM * D_DIM * 2);
    bf16*  Rh    = (bf16*) alloc((size_t)N_DIM * D_DIM * 2);
    bf16*  Rl    = (bf16*) alloc((size_t)N_DIM * D_DIM * 2);
    float* r2    = (float*)alloc((size_t)N_DIM * 4);
    float* Spart = (float*)alloc((size_t)(N_DIM / 128) * B_DIM * 4 * 4);  // 4 MB
    float* Sinv  = (float*)alloc((size_t)B_DIM * H_DIM * 4);
    (void)n_in; (void)in_sizes;

    const size_t PART_BYTES = (size_t)B_DIM * NOUT * 4;              // 8 MB
    // ksplit=8: 256 blocks = exactly 1/CU (128KB LDS), one batch.
    int ksplit = (ws_size >= off + 8 * PART_BYTES) ? 8
               : (ws_size >= off + 4 * PART_BYTES) ? 4 : 2;
    float* parts = (float*)alloc((size_t)ksplit * PART_BYTES);
    int kiters = N_DIM / (64 * ksplit);

    k_prep<<<dim3(PREP_RBLK + PREP_XBLK), 256, 0, stream>>>(x, R, xh, xl, Rh, Rl, r2);
    k_build_V<<<dim3(N_DIM / 64, DOUT_DIM / 32, H_DIM), 256, 0, stream>>>(W, q_raw, Vt);
    k_scores<<<dim3(N_DIM / 128, B_DIM / 128), 256, 0, stream>>>(xh, xl, Rh, Rl, r2, q_raw, eM, Spart);
    k_sreduce<<<dim3(B_DIM * H_DIM / 256), 256, 0, stream>>>(Spart, Sinv);
    k_gemm<<<dim3(NOUT / 256, B_DIM / 256, ksplit), 512, 0, stream>>>(eM, Vt, parts, kiters);
    k_final<<<dim3(B_DIM * NOUT / 4 / 256), 256, 0, stream>>>(parts, Sinv, out, ksplit);
}